// Round 4
// baseline (3740.546 us; speedup 1.0000x reference)
//
#include <hip/hip_runtime.h>
#include <hip/hip_bf16.h>
#include <hip/hip_fp16.h>

typedef __attribute__((ext_vector_type(8))) short short8;
typedef __attribute__((ext_vector_type(4))) float f32x4;

#define TWARM 96
#define SOUT  24
#define WIN   48   // x staging window (timesteps per LDS window)
#define K1 1.44269504089f   // log2(e)
#define K2 2.88539008178f   // 2*log2(e)

__device__ __forceinline__ short f2bf(float f) {
    __hip_bfloat16 h = __float2bfloat16(f);
    return *reinterpret_cast<short*>(&h);
}

// 8 waves/block (512 thr), each wave owns 16 batch rows for all 119 steps.
// Per step: Z[16][256] = x@W + b + H[16][64]@U[64][256] via 32 MFMAs, gates
// in-register (8 trans/elem via product-rcp fusion), h transposed through a
// padded per-wave LDS buffer. x staged in LDS fp16 windows; decode preds
// buffered in LDS and written coalesced at the end.
__global__ void __launch_bounds__(512, 4)
lstm_ar_kernel(const float* __restrict__ gin, const float* __restrict__ gW,
               const float* __restrict__ gU, const float* __restrict__ gb,
               const float* __restrict__ gWd, const float* __restrict__ gbd,
               float* __restrict__ gout, int B)
{
    __shared__ __align__(16) short  U_lds[16384];            // 32 KB, pre-swizzled B-frags
    __shared__ __align__(16) short  h_lds[8][16][72];        // 18 KB, per-wave padded
    __shared__ __align__(16) __half x_lds[128][2 * WIN + 2]; // 24.5 KB; reused for pred out

    const int tid  = threadIdx.x;
    const int wv   = tid >> 6;
    const int lane = tid & 63;
    const int c4   = lane & 15;   // MFMA col / A-row selector
    const int hi   = lane >> 4;   // MFMA k-group / C-row group

    // ---- stage U (coalesced global read, swizzled LDS write) ----
    for (int idx = tid; idx < 16384; idx += 512) {
        int k = idx >> 8, col = idx & 255;
        int dst = (((col >> 4) * 2 + (k >> 5)) * 4 + ((k & 31) >> 3)) * 128
                + (col & 15) * 8 + (k & 7);
        U_lds[dst] = f2bf(gU[idx]);
    }

    // ---- per-lane constants ----
    float W0c[16], W1c[16], bc[16];
#pragma unroll
    for (int n = 0; n < 16; ++n) {
        int col = n * 16 + c4;
        W0c[n] = gW[col];
        W1c[n] = gW[256 + col];
        bc[n]  = gb[col];
    }
    float wdc[4][2];
#pragma unroll
    for (int tt = 0; tt < 4; ++tt) {
        wdc[tt][0] = gWd[(tt * 16 + c4) * 2 + 0];
        wdc[tt][1] = gWd[(tt * 16 + c4) * 2 + 1];
    }
    const float bd0 = gbd[0], bd1 = gbd[1];

    const int rowblk = blockIdx.x * 128;
    const int row0   = rowblk + wv * 16;
    const bool active = (row0 + 15) < B;

    // zero this wave's h buffer
    for (int i = lane; i < 16 * 72; i += 64) (&h_lds[wv][0][0])[i] = 0;

    // ---- block-cooperative x window staging (coalesced, fp16 convert) ----
    const int srow = tid >> 2, sq = tid & 3;    // 4 threads per row, 24 floats each
    auto stage_x = [&](int w) {
        const float* src = gin + (size_t)(rowblk + srow) * (TWARM * 2)
                         + w * (WIN * 2) + sq * 24;
        const bool ok = (rowblk + srow) < B;
#pragma unroll
        for (int m = 0; m < 6; ++m) {
            float4 v = ok ? *reinterpret_cast<const float4*>(src + m * 4)
                          : make_float4(0.f, 0.f, 0.f, 0.f);
            int kk = sq * 24 + m * 4;
            __half2* dst = reinterpret_cast<__half2*>(&x_lds[srow][kk]);
            dst[0] = __floats2half2_rn(v.x, v.y);
            dst[1] = __floats2half2_rn(v.z, v.w);
        }
    };

    stage_x(0);
    __syncthreads();   // U + h-zero + x window 0 all visible

    float c_[4][4], h_[4][4];
#pragma unroll
    for (int tt = 0; tt < 4; ++tt)
#pragma unroll
        for (int r = 0; r < 4; ++r) { c_[tt][r] = 0.f; h_[tt][r] = 0.f; }

    const short* hptr  = &h_lds[wv][0][0] + c4 * 72 + hi * 8;     // A-frag read base
    short*       hwptr = &h_lds[wv][0][0] + (hi * 4) * 72 + c4;   // h write base
    const short* uptr  = U_lds + lane * 8;                        // B-frag read base
    const __half2* xw  = reinterpret_cast<const __half2*>(&x_lds[0][0]);
    const int xbase    = (wv * 16 + hi * 4) * 49;                 // half2-word base

    // ---- one LSTM step ----
    auto lstm_step = [&](const float* x0, const float* x1) {
        f32x4 acc[16];
#pragma unroll
        for (int n = 0; n < 16; ++n)
#pragma unroll
            for (int r = 0; r < 4; ++r)
                acc[n][r] = fmaf(x1[r], W1c[n], fmaf(x0[r], W0c[n], bc[n]));

        short8 a0 = *reinterpret_cast<const short8*>(hptr);
        short8 a1 = *reinterpret_cast<const short8*>(hptr + 32);
#pragma unroll
        for (int n = 0; n < 16; ++n) {
            short8 u0 = *reinterpret_cast<const short8*>(uptr + (n * 2 + 0) * 512);
            short8 u1 = *reinterpret_cast<const short8*>(uptr + (n * 2 + 1) * 512);
            acc[n] = __builtin_amdgcn_mfma_f32_16x16x32_bf16(a0, u0, acc[n], 0, 0, 0);
            acc[n] = __builtin_amdgcn_mfma_f32_16x16x32_bf16(a1, u1, acc[n], 0, 0, 0);
        }

        // gates: i,f,g,o tiles at n = tt, tt+4, tt+8, tt+12.
        // sigma(i)*tanh(g) = (1-eg)*rcp((1+ei)(1+eg)) : one rcp per product.
#pragma unroll
        for (int tt = 0; tt < 4; ++tt)
#pragma unroll
            for (int r = 0; r < 4; ++r) {
                float zi = acc[tt][r];
                float zf = acc[tt + 4][r];
                float zg = acc[tt + 8][r];
                float zo = acc[tt + 12][r];
                float ea = __builtin_amdgcn_exp2f(-K1 * zi);
                float ef = __builtin_amdgcn_exp2f(-K1 * zf);
                float eg = __builtin_amdgcn_exp2f(-K2 * zg);
                float eo = __builtin_amdgcn_exp2f(-K1 * zo);
                float sf = __builtin_amdgcn_rcpf(1.0f + ef);
                float sitg = (1.0f - eg) *
                    __builtin_amdgcn_rcpf((1.0f + ea) * (1.0f + eg));
                float cn = fmaf(sf, c_[tt][r], sitg);
                c_[tt][r] = cn;
                float ec = __builtin_amdgcn_exp2f(-K2 * cn);
                float hn = (1.0f - ec) *
                    __builtin_amdgcn_rcpf((1.0f + eo) * (1.0f + ec));
                h_[tt][r] = hn;
                hwptr[r * 72 + tt * 16] = f2bf(hn);
            }
        __syncthreads();
    };

    // ---- warmup: 96 steps, x from LDS windows ----
#pragma unroll 1
    for (int w = 0; w < TWARM / WIN; ++w) {
        if (w != 0) {
            stage_x(w);       // prior step's barrier fenced all window-(w-1) reads
            __syncthreads();
        }
#pragma unroll 1
        for (int tl = 0; tl < WIN; ++tl) {
            float x0[4], x1[4];
#pragma unroll
            for (int r = 0; r < 4; ++r) {
                float2 xf = __half22float2(xw[xbase + r * 49 + tl]);
                x0[r] = xf.x; x1[r] = xf.y;
            }
            lstm_step(x0, x1);
        }
    }

    // ---- decode ----
    float* xout = reinterpret_cast<float*>(&x_lds[0][0]);   // [128][49] f32 = 25088 B

    auto make_pred = [&](float* p0, float* p1) {
#pragma unroll
        for (int r = 0; r < 4; ++r) {
            float a0 = 0.f, a1 = 0.f;
#pragma unroll
            for (int tt = 0; tt < 4; ++tt) {
                a0 = fmaf(h_[tt][r], wdc[tt][0], a0);
                a1 = fmaf(h_[tt][r], wdc[tt][1], a1);
            }
            p0[r] = a0; p1[r] = a1;
        }
#pragma unroll
        for (int m = 1; m < 16; m <<= 1)
#pragma unroll
            for (int r = 0; r < 4; ++r) {
                p0[r] += __shfl_xor(p0[r], m, 64);
                p1[r] += __shfl_xor(p1[r], m, 64);
            }
#pragma unroll
        for (int r = 0; r < 4; ++r) { p0[r] += bd0; p1[r] += bd1; }
    };
    // stash pred in LDS (x window is dead after warmup); coalesced writeout later
    auto store_pred = [&](int s, const float* p0, const float* p1) {
        if (c4 == 0) {
#pragma unroll
            for (int r = 0; r < 4; ++r) {
                int row = wv * 16 + hi * 4 + r;
                xout[row * 49 + s * 2 + 0] = p0[r];
                xout[row * 49 + s * 2 + 1] = p1[r];
            }
        }
    };

    float p0[4], p1[4];
    make_pred(p0, p1);
    store_pred(0, p0, p1);
#pragma unroll 1
    for (int s = 1; s < SOUT; ++s) {
        lstm_step(p0, p1);          // barrier inside also fences pred stashes
        make_pred(p0, p1);
        store_pred(s, p0, p1);
    }
    __syncthreads();   // all pred stashes visible

    // ---- coalesced block writeout: 128 rows x 48 floats contiguous ----
    {
        const int total = 128 * SOUT * 2;             // 6144 floats
#pragma unroll
        for (int k = 0; k < total / 512; ++k) {
            int f   = tid + k * 512;
            int row = f / (SOUT * 2);
            int j   = f - row * (SOUT * 2);
            if (rowblk + row < B)
                gout[(size_t)(rowblk + row) * (SOUT * 2) + j] = xout[row * 49 + j];
        }
    }
}

extern "C" void kernel_launch(void* const* d_in, const int* in_sizes, int n_in,
                              void* d_out, int out_size, void* d_ws, size_t ws_size,
                              hipStream_t stream) {
    const float* gin  = (const float*)d_in[0];
    const float* gW   = (const float*)d_in[1];
    const float* gU   = (const float*)d_in[2];
    const float* gb   = (const float*)d_in[3];
    const float* gWd  = (const float*)d_in[4];
    const float* gbd  = (const float*)d_in[5];
    float* gout = (float*)d_out;

    const int B = in_sizes[0] / (TWARM * 2);
    const int blocks = (B + 127) / 128;
    lstm_ar_kernel<<<blocks, 512, 0, stream>>>(gin, gW, gU, gb, gWd, gbd, gout, B);
}

// Round 5
// 3571.633 us; speedup vs baseline: 1.0473x; 1.0473x over previous
//
#include <hip/hip_runtime.h>
#include <hip/hip_bf16.h>
#include <hip/hip_fp16.h>

typedef __attribute__((ext_vector_type(8))) short short8;
typedef __attribute__((ext_vector_type(4))) float f32x4;

#define TWARM 96
#define SOUT  24
#define WIN   8
#define NW    (TWARM / WIN)
#define K1 1.44269504089f   // log2(e)
#define K2 2.88539008178f   // 2*log2(e)

// Intra-wave LDS write->read ordering fence (rule #18: sched_barrier after waitcnt)
#define LGKM_FENCE() do { \
    asm volatile("s_waitcnt lgkmcnt(0)" ::: "memory"); \
    __builtin_amdgcn_sched_barrier(0); \
} while (0)

static __device__ __forceinline__ short f2bf(float f) {
    __hip_bfloat16 h = __float2bfloat16(f);
    return *reinterpret_cast<short*>(&h);
}
static __device__ __forceinline__ float bf2f(short s) {
    unsigned u = ((unsigned)(unsigned short)s) << 16;
    return __builtin_bit_cast(float, u);
}

// One wave owns 16 batch rows for all 119 steps; waves are fully independent
// (no per-step barrier). Per step: Z'[16][256] = -K1*(x@W + b + H@U) via
// 32 MFMAs (U/W/b pre-scaled by -K1), gates in-register in two 8-tile halves
// (acc peak 32 regs), h transposed through a per-wave padded LDS buffer with
// waitcnt-only fencing. x lives in per-lane fp16 register windows (shfl
// redistribution). Decode preds buffered in fp16 LDS, coalesced writeout.
__global__ void __launch_bounds__(256, 3)
lstm_ar_kernel(const float* __restrict__ gin, const float* __restrict__ gW,
               const float* __restrict__ gU, const float* __restrict__ gb,
               const float* __restrict__ gWd, const float* __restrict__ gbd,
               float* __restrict__ gout, int B)
{
    __shared__ __align__(16) short   U_lds[16384];          // 32 KB, swizzled B-frags
    __shared__ __align__(16) short   h_lds[4][16][72];      // 9 KB, per-wave padded
    __shared__ __align__(8)  __half2 pred_lds[4][16][SOUT]; // 6 KB

    const int tid  = threadIdx.x;
    const int wv   = tid >> 6;
    const int lane = tid & 63;
    const int c4   = lane & 15;   // MFMA col / A-row selector
    const int hi   = lane >> 4;   // MFMA k-group / C-row group

    // ---- stage U scaled by -K1 (coalesced read, swizzled LDS write) ----
    for (int base = tid * 4; base < 16384; base += 1024) {
        float4 v = *reinterpret_cast<const float4*>(gU + base);
        float vv[4] = {v.x, v.y, v.z, v.w};
#pragma unroll
        for (int e = 0; e < 4; ++e) {
            int idx = base + e, k = idx >> 8, col = idx & 255;
            int dst = (((col >> 4) * 2 + (k >> 5)) * 4 + ((k & 31) >> 3)) * 128
                    + (col & 15) * 8 + (k & 7);
            U_lds[dst] = f2bf(-K1 * vv[e]);
        }
    }

    // ---- per-lane constants (W, b pre-scaled by -K1; Wd, bd true scale) ----
    float W0c[16], W1c[16], bc[16];
#pragma unroll
    for (int n = 0; n < 16; ++n) {
        int col = n * 16 + c4;
        W0c[n] = -K1 * gW[col];
        W1c[n] = -K1 * gW[256 + col];
        bc[n]  = -K1 * gb[col];
    }
    float wdc[4][2];
#pragma unroll
    for (int tt = 0; tt < 4; ++tt) {
        wdc[tt][0] = gWd[(tt * 16 + c4) * 2 + 0];
        wdc[tt][1] = gWd[(tt * 16 + c4) * 2 + 1];
    }
    const float bd0 = gbd[0], bd1 = gbd[1];

    const int rowblk = blockIdx.x * 64;
    const int row0   = rowblk + wv * 16;
    const bool active = (row0 + 15) < B;

    // zero this wave's h buffer (intra-wave; fence before first read)
    for (int i = lane; i < 16 * 72; i += 64) (&h_lds[wv][0][0])[i] = 0;
    LGKM_FENCE();
    __syncthreads();   // U staged & visible to all waves

    float c_[4][4], h_[4][4];
#pragma unroll
    for (int tt = 0; tt < 4; ++tt)
#pragma unroll
        for (int r = 0; r < 4; ++r) { c_[tt][r] = 0.f; h_[tt][r] = 0.f; }

    const short* hptr  = &h_lds[wv][0][0] + c4 * 72 + hi * 8;     // A-frag read base
    short*       hwptr = &h_lds[wv][0][0] + (hi * 4) * 72 + c4;   // h write base
    const short* uptr  = U_lds + lane * 8;                        // B-frag read base

    // one LSTM step; acc in z' = -K1*z units; two 8-tile halves
    auto lstm_step = [&](const float x0[4], const float x1[4], bool save_h) {
        short8 a0 = *reinterpret_cast<const short8*>(hptr);
        short8 a1 = *reinterpret_cast<const short8*>(hptr + 32);
#pragma unroll
        for (int half = 0; half < 2; ++half) {
            f32x4 acc[8];
#pragma unroll
            for (int j = 0; j < 8; ++j) {
                const int tt = half * 2 + (j & 1);
                const int n  = tt + 4 * (j >> 1);
#pragma unroll
                for (int r = 0; r < 4; ++r)
                    acc[j][r] = fmaf(x1[r], W1c[n], fmaf(x0[r], W0c[n], bc[n]));
            }
#pragma unroll
            for (int j = 0; j < 8; ++j) {
                const int tt = half * 2 + (j & 1);
                const int n  = tt + 4 * (j >> 1);
                short8 u0 = *reinterpret_cast<const short8*>(uptr + (n * 2 + 0) * 512);
                short8 u1 = *reinterpret_cast<const short8*>(uptr + (n * 2 + 1) * 512);
                acc[j] = __builtin_amdgcn_mfma_f32_16x16x32_bf16(a0, u0, acc[j], 0, 0, 0);
                acc[j] = __builtin_amdgcn_mfma_f32_16x16x32_bf16(a1, u1, acc[j], 0, 0, 0);
            }
            // gates: for tt = half*2+q, tiles i=acc[q], f=acc[q+2], g=acc[q+4], o=acc[q+6]
#pragma unroll
            for (int q = 0; q < 2; ++q) {
                const int tt = half * 2 + q;
#pragma unroll
                for (int r = 0; r < 4; ++r) {
                    float ea  = __builtin_amdgcn_exp2f(acc[q][r]);        // e^{-zi}
                    float ef  = __builtin_amdgcn_exp2f(acc[q + 2][r]);    // e^{-zf}
                    float eg0 = __builtin_amdgcn_exp2f(acc[q + 4][r]);    // e^{-zg}
                    float eo  = __builtin_amdgcn_exp2f(acc[q + 6][r]);    // e^{-zo}
                    float eg  = eg0 * eg0;                                // e^{-2zg}
                    float sf  = __builtin_amdgcn_rcpf(1.0f + ef);
                    float sitg = (1.0f - eg) *
                        __builtin_amdgcn_rcpf((1.0f + ea) * (1.0f + eg));
                    float cn = fmaf(sf, c_[tt][r], sitg);
                    c_[tt][r] = cn;
                    float ec = __builtin_amdgcn_exp2f(-K2 * cn);
                    float hn = (1.0f - ec) *
                        __builtin_amdgcn_rcpf((1.0f + eo) * (1.0f + ec));
                    if (save_h) h_[tt][r] = hn;
                    hwptr[r * 72 + tt * 16] = f2bf(hn);
                }
            }
        }
        LGKM_FENCE();   // h writes land before next step's A-frag reads
    };

    if (active) {
        // ---- warmup: x in per-lane fp16 register windows, shfl redistribution ----
        const float* xsrc = gin + (size_t)(row0 + c4) * (TWARM * 2);  // lane's own row
        __half2 xc[8];
        {
            float4 p[4];
#pragma unroll
            for (int j = 0; j < 4; ++j)
                p[j] = *reinterpret_cast<const float4*>(xsrc + j * 4);
#pragma unroll
            for (int j = 0; j < 4; ++j) {
                xc[2 * j + 0] = __floats2half2_rn(p[j].x, p[j].y);
                xc[2 * j + 1] = __floats2half2_rn(p[j].z, p[j].w);
            }
        }

#pragma unroll 1
        for (int w = 0; w < NW; ++w) {
            float4 nx[4];
            if (w + 1 < NW) {
#pragma unroll
                for (int j = 0; j < 4; ++j)
                    nx[j] = *reinterpret_cast<const float4*>(xsrc + (w + 1) * 16 + j * 4);
            }
#pragma unroll
            for (int tl = 0; tl < WIN; ++tl) {
                float x0[4], x1[4];
                float xf = __builtin_bit_cast(float, xc[tl]);
#pragma unroll
                for (int r = 0; r < 4; ++r) {
                    float xs = __shfl(xf, hi * 4 + r, 64);
                    __half2 hx = __builtin_bit_cast(__half2, xs);
                    x0[r] = __low2float(hx);
                    x1[r] = __high2float(hx);
                }
                lstm_step(x0, x1, false);
            }
            if (w + 1 < NW) {
#pragma unroll
                for (int j = 0; j < 4; ++j) {
                    xc[2 * j + 0] = __floats2half2_rn(nx[j].x, nx[j].y);
                    xc[2 * j + 1] = __floats2half2_rn(nx[j].z, nx[j].w);
                }
            }
        }

        // rebuild h_ (f32) from the bf16 LDS copy once after warmup
#pragma unroll
        for (int tt = 0; tt < 4; ++tt)
#pragma unroll
            for (int r = 0; r < 4; ++r)
                h_[tt][r] = bf2f((&h_lds[wv][0][0])[(hi * 4 + r) * 72 + tt * 16 + c4]);

        // ---- decode ----
        auto make_pred = [&](float* p0, float* p1) {
#pragma unroll
            for (int r = 0; r < 4; ++r) {
                float a0 = 0.f, a1 = 0.f;
#pragma unroll
                for (int tt = 0; tt < 4; ++tt) {
                    a0 = fmaf(h_[tt][r], wdc[tt][0], a0);
                    a1 = fmaf(h_[tt][r], wdc[tt][1], a1);
                }
                p0[r] = a0; p1[r] = a1;
            }
#pragma unroll
            for (int m = 1; m < 16; m <<= 1)
#pragma unroll
                for (int r = 0; r < 4; ++r) {
                    p0[r] += __shfl_xor(p0[r], m, 64);
                    p1[r] += __shfl_xor(p1[r], m, 64);
                }
#pragma unroll
            for (int r = 0; r < 4; ++r) { p0[r] += bd0; p1[r] += bd1; }
        };

        float p0[4], p1[4];
        make_pred(p0, p1);
        if (c4 == 0) {
#pragma unroll
            for (int r = 0; r < 4; ++r)
                pred_lds[wv][hi * 4 + r][0] = __floats2half2_rn(p0[r], p1[r]);
        }
#pragma unroll 1
        for (int s = 1; s < SOUT; ++s) {
            lstm_step(p0, p1, true);
            make_pred(p0, p1);
            if (c4 == 0) {
#pragma unroll
                for (int r = 0; r < 4; ++r)
                    pred_lds[wv][hi * 4 + r][s] = __floats2half2_rn(p0[r], p1[r]);
            }
        }
    }

    __syncthreads();   // all waves' pred stashes visible

    // ---- coalesced writeout: 64 rows x 48 floats ----
#pragma unroll
    for (int k = 0; k < 12; ++k) {
        int f   = tid + k * 256;
        int row = f / (SOUT * 2);
        int j   = f - row * (SOUT * 2);
        __half2 hv = pred_lds[row >> 4][row & 15][j >> 1];
        float val = (j & 1) ? __high2float(hv) : __low2float(hv);
        if (rowblk + row < B)
            gout[(size_t)(rowblk + row) * (SOUT * 2) + j] = val;
    }
}

extern "C" void kernel_launch(void* const* d_in, const int* in_sizes, int n_in,
                              void* d_out, int out_size, void* d_ws, size_t ws_size,
                              hipStream_t stream) {
    const float* gin  = (const float*)d_in[0];
    const float* gW   = (const float*)d_in[1];
    const float* gU   = (const float*)d_in[2];
    const float* gb   = (const float*)d_in[3];
    const float* gWd  = (const float*)d_in[4];
    const float* gbd  = (const float*)d_in[5];
    float* gout = (float*)d_out;

    const int B = in_sizes[0] / (TWARM * 2);
    const int blocks = (B + 63) / 64;
    lstm_ar_kernel<<<blocks, 256, 0, stream>>>(gin, gW, gU, gb, gWd, gbd, gout, B);
}

// Round 6
// 1657.455 us; speedup vs baseline: 2.2568x; 2.1549x over previous
//
#include <hip/hip_runtime.h>
#include <hip/hip_bf16.h>
#include <hip/hip_fp16.h>

typedef __attribute__((ext_vector_type(8))) short short8;
typedef __attribute__((ext_vector_type(4))) float f32x4;

#define TWARM 96
#define SOUT  24
#define WIN   24   // x staging window (timesteps per LDS window)
#define NWIN  (TWARM / WIN)
#define K1 1.44269504089f   // log2(e)
#define K2 2.88539008178f   // 2*log2(e)

__device__ __forceinline__ short f2bf(float f) {
    __hip_bfloat16 h = __float2bfloat16(f);
    return *reinterpret_cast<short*>(&h);
}

// One wave owns 16 batch rows for the whole 119-step sequence.
// Per step: Z'[16][256] = -K*(x@W + b + H[16][64]@U[64][256]) via 32 MFMAs
// (U/W/b staged pre-scaled by -log2e, g-columns by -2*log2e), gates
// in-register, h transposed through a padded per-wave LDS buffer.
// x staged in fp16 LDS windows (4 x 24 steps); decode preds stashed fp16 in
// the dead x buffer, coalesced writeout. No inline asm; one barrier per step.
__global__ void __launch_bounds__(256, 2)
lstm_ar_kernel(const float* __restrict__ gin, const float* __restrict__ gW,
               const float* __restrict__ gU, const float* __restrict__ gb,
               const float* __restrict__ gWd, const float* __restrict__ gbd,
               float* __restrict__ gout, int B)
{
    __shared__ __align__(16) short  U_lds[16384];       // 32 KB, pre-swizzled B-frags
    __shared__ __align__(16) short  h_lds[4][16][72];   // 9 KB, per-wave padded
    __shared__ __align__(16) __half x_lds[64][52];      // 6.5 KB; reused for pred out

    const int tid  = threadIdx.x;
    const int wv   = tid >> 6;
    const int lane = tid & 63;
    const int c4   = lane & 15;   // MFMA col / A-row selector
    const int hi   = lane >> 4;   // MFMA k-group / C-row group

    // ---- stage U (coalesced read, swizzled LDS write, gate-scale folded) ----
    for (int idx = tid; idx < 16384; idx += 256) {
        int k = idx >> 8, col = idx & 255;
        float sc = ((col >> 6) == 2) ? -K2 : -K1;   // g columns get -2*log2e
        int dst = (((col >> 4) * 2 + (k >> 5)) * 4 + ((k & 31) >> 3)) * 128
                + (col & 15) * 8 + (k & 7);
        U_lds[dst] = f2bf(sc * gU[idx]);
    }

    // ---- per-lane constants (same scale folding on W, b) ----
    float W0c[16], W1c[16], bc[16];
#pragma unroll
    for (int n = 0; n < 16; ++n) {
        int col = n * 16 + c4;
        float sc = (n >= 8 && n < 12) ? -K2 : -K1;
        W0c[n] = sc * gW[col];
        W1c[n] = sc * gW[256 + col];
        bc[n]  = sc * gb[col];
    }
    float wdc[4][2];
#pragma unroll
    for (int tt = 0; tt < 4; ++tt) {
        wdc[tt][0] = gWd[(tt * 16 + c4) * 2 + 0];
        wdc[tt][1] = gWd[(tt * 16 + c4) * 2 + 1];
    }
    const float bd0 = gbd[0], bd1 = gbd[1];

    const int rowblk = blockIdx.x * 64;
    const int row0   = rowblk + wv * 16;

    // zero this wave's h buffer
    for (int i = lane; i < 16 * 72; i += 64) (&h_lds[wv][0][0])[i] = 0;

    // ---- block-cooperative x window staging (coalesced, fp16 convert) ----
    const int srow = tid >> 2, sq = tid & 3;    // 4 threads per row, 12 floats each
    auto stage_x = [&](int w) {
        const float* src = gin + (size_t)(rowblk + srow) * (TWARM * 2)
                         + w * (WIN * 2) + sq * 12;
        const bool ok = (rowblk + srow) < B;
#pragma unroll
        for (int m = 0; m < 3; ++m) {
            float4 v = ok ? *reinterpret_cast<const float4*>(src + m * 4)
                          : make_float4(0.f, 0.f, 0.f, 0.f);
            __half2* dst = reinterpret_cast<__half2*>(&x_lds[0][0])
                         + srow * 26 + sq * 6 + m * 2;
            dst[0] = __floats2half2_rn(v.x, v.y);
            dst[1] = __floats2half2_rn(v.z, v.w);
        }
    };

    stage_x(0);
    __syncthreads();   // U + h-zero + x window 0 all visible

    float c_[4][4], h_[4][4];
#pragma unroll
    for (int tt = 0; tt < 4; ++tt)
#pragma unroll
        for (int r = 0; r < 4; ++r) { c_[tt][r] = 0.f; h_[tt][r] = 0.f; }

    const short* hptr  = &h_lds[wv][0][0] + c4 * 72 + hi * 8;     // A-frag read base
    short*       hwptr = &h_lds[wv][0][0] + (hi * 4) * 72 + c4;   // h write base
    const short* uptr  = U_lds + lane * 8;                        // B-frag read base
    const __half2* xw  = reinterpret_cast<const __half2*>(&x_lds[0][0]);
    const int xbase    = (wv * 16 + hi * 4) * 26;                 // half2-word base

    // ---- one LSTM step (acc is z' = -K*z; gates are exp2(acc) directly) ----
    auto lstm_step = [&](const float* x0, const float* x1) {
        f32x4 acc[16];
#pragma unroll
        for (int n = 0; n < 16; ++n)
#pragma unroll
            for (int r = 0; r < 4; ++r)
                acc[n][r] = fmaf(x1[r], W1c[n], fmaf(x0[r], W0c[n], bc[n]));

        short8 a0 = *reinterpret_cast<const short8*>(hptr);
        short8 a1 = *reinterpret_cast<const short8*>(hptr + 32);
#pragma unroll
        for (int n = 0; n < 16; ++n) {
            short8 u0 = *reinterpret_cast<const short8*>(uptr + (n * 2 + 0) * 512);
            short8 u1 = *reinterpret_cast<const short8*>(uptr + (n * 2 + 1) * 512);
            acc[n] = __builtin_amdgcn_mfma_f32_16x16x32_bf16(a0, u0, acc[n], 0, 0, 0);
            acc[n] = __builtin_amdgcn_mfma_f32_16x16x32_bf16(a1, u1, acc[n], 0, 0, 0);
        }

        // tiles [i | f | g | o] at n = tt, tt+4, tt+8, tt+12
        // ea=e^{-zi}, ef=e^{-zf}, eg=e^{-2zg}, eo=e^{-zo}
        // sig(i)*tanh(g) = (1-eg)*rcp((1+ea)(1+eg)); one rcp per product.
#pragma unroll
        for (int tt = 0; tt < 4; ++tt)
#pragma unroll
            for (int r = 0; r < 4; ++r) {
                float ea = __builtin_amdgcn_exp2f(acc[tt][r]);
                float ef = __builtin_amdgcn_exp2f(acc[tt + 4][r]);
                float eg = __builtin_amdgcn_exp2f(acc[tt + 8][r]);
                float eo = __builtin_amdgcn_exp2f(acc[tt + 12][r]);
                float sf = __builtin_amdgcn_rcpf(1.0f + ef);
                float sitg = (1.0f - eg) *
                    __builtin_amdgcn_rcpf((1.0f + ea) * (1.0f + eg));
                float cn = fmaf(sf, c_[tt][r], sitg);
                c_[tt][r] = cn;
                float ec = __builtin_amdgcn_exp2f(-K2 * cn);
                float hn = (1.0f - ec) *
                    __builtin_amdgcn_rcpf((1.0f + eo) * (1.0f + ec));
                h_[tt][r] = hn;
                hwptr[r * 72 + tt * 16] = f2bf(hn);
            }
        __syncthreads();
    };

    // ---- warmup: 96 steps, x from LDS windows ----
#pragma unroll 1
    for (int w = 0; w < NWIN; ++w) {
        if (w != 0) {
            stage_x(w);       // prior step's barrier fenced all window-(w-1) reads
            __syncthreads();
        }
#pragma unroll 1
        for (int tl = 0; tl < WIN; ++tl) {
            float x0[4], x1[4];
#pragma unroll
            for (int r = 0; r < 4; ++r) {
                float2 xf = __half22float2(xw[xbase + r * 26 + tl]);
                x0[r] = xf.x; x1[r] = xf.y;
            }
            lstm_step(x0, x1);
        }
    }

    // ---- decode: pred = h@Wd + bd, butterfly over the 16-lane col group ----
    __half2* pred_h2 = reinterpret_cast<__half2*>(&x_lds[0][0]);  // x dead now

    auto make_pred = [&](float* p0, float* p1) {
#pragma unroll
        for (int r = 0; r < 4; ++r) {
            float a0 = 0.f, a1 = 0.f;
#pragma unroll
            for (int tt = 0; tt < 4; ++tt) {
                a0 = fmaf(h_[tt][r], wdc[tt][0], a0);
                a1 = fmaf(h_[tt][r], wdc[tt][1], a1);
            }
            p0[r] = a0; p1[r] = a1;
        }
#pragma unroll
        for (int m = 1; m < 16; m <<= 1)
#pragma unroll
            for (int r = 0; r < 4; ++r) {
                p0[r] += __shfl_xor(p0[r], m, 64);
                p1[r] += __shfl_xor(p1[r], m, 64);
            }
#pragma unroll
        for (int r = 0; r < 4; ++r) { p0[r] += bd0; p1[r] += bd1; }
    };
    // stash pred in LDS (fp16, output precision only; feedback stays f32 regs)
    auto store_pred = [&](int s, const float* p0, const float* p1) {
        if (c4 == 0) {
#pragma unroll
            for (int r = 0; r < 4; ++r)
                pred_h2[(wv * 16 + hi * 4 + r) * 26 + s] =
                    __floats2half2_rn(p0[r], p1[r]);
        }
    };

    float p0[4], p1[4];
    make_pred(p0, p1);
    store_pred(0, p0, p1);
#pragma unroll 1
    for (int s = 1; s < SOUT; ++s) {
        lstm_step(p0, p1);          // barrier inside also fences pred stashes
        make_pred(p0, p1);
        store_pred(s, p0, p1);
    }
    __syncthreads();   // all pred stashes visible

    // ---- coalesced writeout: 64 rows x 48 floats contiguous ----
#pragma unroll
    for (int k = 0; k < 12; ++k) {
        int f   = tid + k * 256;
        int row = f / (SOUT * 2);
        int j   = f - row * (SOUT * 2);
        __half2 hv = pred_h2[row * 26 + (j >> 1)];
        float val = (j & 1) ? __high2float(hv) : __low2float(hv);
        if (rowblk + row < B)
            gout[(size_t)(rowblk + row) * (SOUT * 2) + j] = val;
    }
}

extern "C" void kernel_launch(void* const* d_in, const int* in_sizes, int n_in,
                              void* d_out, int out_size, void* d_ws, size_t ws_size,
                              hipStream_t stream) {
    const float* gin  = (const float*)d_in[0];
    const float* gW   = (const float*)d_in[1];
    const float* gU   = (const float*)d_in[2];
    const float* gb   = (const float*)d_in[3];
    const float* gWd  = (const float*)d_in[4];
    const float* gbd  = (const float*)d_in[5];
    float* gout = (float*)d_out;

    const int B = in_sizes[0] / (TWARM * 2);
    const int blocks = (B + 63) / 64;
    lstm_ar_kernel<<<blocks, 256, 0, stream>>>(gin, gW, gU, gb, gWd, gbd, gout, B);
}

// Round 7
// 901.171 us; speedup vs baseline: 4.1508x; 1.8392x over previous
//
#include <hip/hip_runtime.h>
#include <hip/hip_bf16.h>
#include <hip/hip_fp16.h>

typedef __attribute__((ext_vector_type(8))) short short8;
typedef __attribute__((ext_vector_type(4))) float f32x4;

#define TWARM 96
#define SOUT  24
#define WIN   24   // x staging window (timesteps per per-wave LDS window)
#define NWIN  (TWARM / WIN)
#define K1 1.44269504089f   // log2(e)
#define K2 2.88539008178f   // 2*log2(e)

// Intra-wave LDS write->read ordering fence (rule #18: sched_barrier after waitcnt)
#define LGKM_FENCE() do { \
    asm volatile("s_waitcnt lgkmcnt(0)" ::: "memory"); \
    __builtin_amdgcn_sched_barrier(0); \
} while (0)

static __device__ __forceinline__ short f2bf(float f) {
    __hip_bfloat16 h = __float2bfloat16(f);
    return *reinterpret_cast<short*>(&h);
}
static __device__ __forceinline__ float bf2f(short s) {
    unsigned u = ((unsigned)(unsigned short)s) << 16;
    return __builtin_bit_cast(float, u);
}

// One wave owns 16 batch rows for all 119 steps; after the single init
// barrier, waves are fully independent (per-wave x staging, per-wave pred
// writeout, waitcnt+sched_barrier fencing for the per-wave h LDS round trip).
// Per step: Z' = -K*(x@W + b + H[16][64]@U[64][256]) via 32 MFMAs in two
// 8-tile halves (acc peak 32 regs); U/W/b pre-scaled (-log2e, g cols
// -2*log2e); c kept pre-scaled by -2*log2e so gates are exp2() directly.
__global__ void __launch_bounds__(256, 2)
lstm_ar_kernel(const float* __restrict__ gin, const float* __restrict__ gW,
               const float* __restrict__ gU, const float* __restrict__ gb,
               const float* __restrict__ gWd, const float* __restrict__ gbd,
               float* __restrict__ gout, int B)
{
    __shared__ __align__(16) short    U_lds[16384];        // 32 KB, swizzled B-frags
    __shared__ __align__(16) short    h_lds[4][16][72];    // 9 KB, per-wave padded
    __shared__ __align__(16) unsigned x_lds[4][16][WIN];   // 6 KB fp16-pair x; reused for preds
    __shared__ float wdc_lds[4][2][16];                    // 512 B

    const int tid  = threadIdx.x;
    const int wv   = tid >> 6;
    const int lane = tid & 63;
    const int c4   = lane & 15;   // MFMA col / A-row selector
    const int hi   = lane >> 4;   // MFMA k-group / C-row group

    // ---- stage U (coalesced read, swizzled LDS write, gate-scale folded) ----
    for (int idx = tid; idx < 16384; idx += 256) {
        int k = idx >> 8, col = idx & 255;
        float sc = ((col >> 6) == 2) ? -K2 : -K1;   // g columns get -2*log2e
        int dst = (((col >> 4) * 2 + (k >> 5)) * 4 + ((k & 31) >> 3)) * 128
                + (col & 15) * 8 + (k & 7);
        U_lds[dst] = f2bf(sc * gU[idx]);
    }
    // ---- Wd table ----
    if (tid < 128) {
        int tt = tid >> 5, j = (tid >> 4) & 1, cc = tid & 15;
        wdc_lds[tt][j][cc] = gWd[(tt * 16 + cc) * 2 + j];
    }

    // ---- per-lane constants: W packed fp16 (scale folded), b f32 ----
    unsigned Wp[16]; float bc[16];
#pragma unroll
    for (int n = 0; n < 16; ++n) {
        int col = n * 16 + c4;
        float sc = (n >= 8 && n < 12) ? -K2 : -K1;
        __half2 wp = __floats2half2_rn(sc * gW[col], sc * gW[256 + col]);
        Wp[n] = __builtin_bit_cast(unsigned, wp);
        bc[n] = sc * gb[col];
    }
    const float bd0 = gbd[0], bd1 = gbd[1];

    const int row0   = blockIdx.x * 64 + wv * 16;
    const bool active = (row0 + 15) < B;

    // zero this wave's h buffer
    for (int i = lane; i < 16 * 72; i += 64) (&h_lds[wv][0][0])[i] = 0;

    // ---- per-wave x window staging: 16 rows x WIN steps, fp16 pairs ----
    const int xrow = lane >> 2, xq = lane & 3;   // 4 lanes/row, 12 floats each
    auto stage_x = [&](int w) {
        const float* src = gin + (size_t)(row0 + xrow) * (TWARM * 2)
                         + w * (WIN * 2) + xq * 12;
#pragma unroll
        for (int m = 0; m < 3; ++m) {
            float4 v = *reinterpret_cast<const float4*>(src + m * 4);
            uint2 pk;
            pk.x = __builtin_bit_cast(unsigned, __floats2half2_rn(v.x, v.y));
            pk.y = __builtin_bit_cast(unsigned, __floats2half2_rn(v.z, v.w));
            *reinterpret_cast<uint2*>(&x_lds[wv][xrow][xq * 6 + m * 2]) = pk;
        }
        LGKM_FENCE();   // window visible to this wave before first read
    };

    if (active) stage_x(0);
    __syncthreads();    // the ONLY block barrier: U + wdc staged & visible
    if (!active) return;

    float c_[4][4];     // pre-scaled: c' = -K2 * c
#pragma unroll
    for (int tt = 0; tt < 4; ++tt)
#pragma unroll
        for (int r = 0; r < 4; ++r) c_[tt][r] = 0.f;

    const short* hptr  = &h_lds[wv][0][0] + c4 * 72 + hi * 8;     // A-frag read base
    short*       hwptr = &h_lds[wv][0][0] + (hi * 4) * 72 + c4;   // h write base
    const short* uptr  = U_lds + lane * 8;                        // B-frag read base

    float h_[4][4];     // live during decode only

    // ---- one LSTM step; acc is z' = -K*z; two 8-tile halves ----
    auto lstm_step = [&](const float x0[4], const float x1[4], bool save_h) {
        short8 a0 = *reinterpret_cast<const short8*>(hptr);
        short8 a1 = *reinterpret_cast<const short8*>(hptr + 32);
#pragma unroll
        for (int half = 0; half < 2; ++half) {
            f32x4 acc[8];
#pragma unroll
            for (int j = 0; j < 8; ++j) {
                const int n = (half * 2 + (j & 1)) + 4 * (j >> 1);
                __half2 wp = __builtin_bit_cast(__half2, Wp[n]);
                float w0 = __low2float(wp), w1 = __high2float(wp);
#pragma unroll
                for (int r = 0; r < 4; ++r)
                    acc[j][r] = fmaf(x1[r], w1, fmaf(x0[r], w0, bc[n]));
            }
#pragma unroll
            for (int j = 0; j < 8; ++j) {
                const int n = (half * 2 + (j & 1)) + 4 * (j >> 1);
                short8 u0 = *reinterpret_cast<const short8*>(uptr + (n * 2 + 0) * 512);
                short8 u1 = *reinterpret_cast<const short8*>(uptr + (n * 2 + 1) * 512);
                acc[j] = __builtin_amdgcn_mfma_f32_16x16x32_bf16(a0, u0, acc[j], 0, 0, 0);
                acc[j] = __builtin_amdgcn_mfma_f32_16x16x32_bf16(a1, u1, acc[j], 0, 0, 0);
            }
            // gates: tt = half*2+q; i=acc[q], f=acc[q+2], g=acc[q+4], o=acc[q+6]
            // ea=e^{-zi}, ef=e^{-zf}, eg=e^{-2zg}, eo=e^{-zo}
            // c' update: c'n = sf*c' + (K2*eg - K2)*rcp((1+ea)(1+eg)); ec = exp2(c'n)
#pragma unroll
            for (int q = 0; q < 2; ++q) {
                const int tt = half * 2 + q;
#pragma unroll
                for (int r = 0; r < 4; ++r) {
                    float ea = __builtin_amdgcn_exp2f(acc[q][r]);
                    float ef = __builtin_amdgcn_exp2f(acc[q + 2][r]);
                    float eg = __builtin_amdgcn_exp2f(acc[q + 4][r]);
                    float eo = __builtin_amdgcn_exp2f(acc[q + 6][r]);
                    float sf = __builtin_amdgcn_rcpf(1.0f + ef);
                    float sg = fmaf(eg, K2, -K2) *
                        __builtin_amdgcn_rcpf((1.0f + ea) * (1.0f + eg));
                    float cn = fmaf(sf, c_[tt][r], sg);
                    c_[tt][r] = cn;
                    float ec = __builtin_amdgcn_exp2f(cn);
                    float hn = (1.0f - ec) *
                        __builtin_amdgcn_rcpf((1.0f + eo) * (1.0f + ec));
                    if (save_h) h_[tt][r] = hn;
                    hwptr[r * 72 + tt * 16] = f2bf(hn);
                }
            }
        }
        LGKM_FENCE();   // h writes land before next step's A-frag reads
    };

    // ---- warmup: 96 steps, x from this wave's LDS windows ----
#pragma unroll 1
    for (int w = 0; w < NWIN; ++w) {
        if (w != 0) stage_x(w);   // prior step's fence ordered old-window reads
#pragma unroll 1
        for (int tl = 0; tl < WIN; ++tl) {
            float x0[4], x1[4];
#pragma unroll
            for (int r = 0; r < 4; ++r) {
                __half2 hx = __builtin_bit_cast(__half2, x_lds[wv][hi * 4 + r][tl]);
                x0[r] = __low2float(hx);
                x1[r] = __high2float(hx);
            }
            lstm_step(x0, x1, false);
        }
    }

    // rebuild h_ (f32) from the bf16 LDS copy once after warmup
#pragma unroll
    for (int tt = 0; tt < 4; ++tt)
#pragma unroll
        for (int r = 0; r < 4; ++r)
            h_[tt][r] = bf2f((&h_lds[wv][0][0])[(hi * 4 + r) * 72 + tt * 16 + c4]);

    // hoist Wd for this lane's cols (decode-only registers)
    float wdc[4][2];
#pragma unroll
    for (int tt = 0; tt < 4; ++tt) {
        wdc[tt][0] = wdc_lds[tt][0][c4];
        wdc[tt][1] = wdc_lds[tt][1][c4];
    }

    // ---- decode: pred = h@Wd + bd, butterfly over the 16-lane col group ----
    auto make_pred = [&](float* p0, float* p1) {
#pragma unroll
        for (int r = 0; r < 4; ++r) {
            float a0 = 0.f, a1 = 0.f;
#pragma unroll
            for (int tt = 0; tt < 4; ++tt) {
                a0 = fmaf(h_[tt][r], wdc[tt][0], a0);
                a1 = fmaf(h_[tt][r], wdc[tt][1], a1);
            }
            p0[r] = a0; p1[r] = a1;
        }
#pragma unroll
        for (int m = 1; m < 16; m <<= 1)
#pragma unroll
            for (int r = 0; r < 4; ++r) {
                p0[r] += __shfl_xor(p0[r], m, 64);
                p1[r] += __shfl_xor(p1[r], m, 64);
            }
#pragma unroll
        for (int r = 0; r < 4; ++r) { p0[r] += bd0; p1[r] += bd1; }
    };
    // stash pred fp16 in this wave's (dead) x window; feedback stays f32 regs
    auto store_pred = [&](int s, const float* p0, const float* p1) {
        if (c4 == 0) {
#pragma unroll
            for (int r = 0; r < 4; ++r)
                x_lds[wv][hi * 4 + r][s] =
                    __builtin_bit_cast(unsigned, __floats2half2_rn(p0[r], p1[r]));
        }
    };

    float p0[4], p1[4];
    make_pred(p0, p1);
    store_pred(0, p0, p1);
#pragma unroll 1
    for (int s = 1; s < SOUT; ++s) {
        lstm_step(p0, p1, true);
        make_pred(p0, p1);
        store_pred(s, p0, p1);
    }
    LGKM_FENCE();   // all pred stashes of this wave visible to this wave

    // ---- per-wave coalesced writeout: 16 rows x 48 floats ----
#pragma unroll
    for (int m = 0; m < 6; ++m) {
        unsigned u = x_lds[wv][xrow][xq * 6 + m];
        __half2 hv = __builtin_bit_cast(__half2, u);
        *reinterpret_cast<float2*>(
            gout + (size_t)(row0 + xrow) * (SOUT * 2) + xq * 12 + m * 2) =
            make_float2(__low2float(hv), __high2float(hv));
    }
}

extern "C" void kernel_launch(void* const* d_in, const int* in_sizes, int n_in,
                              void* d_out, int out_size, void* d_ws, size_t ws_size,
                              hipStream_t stream) {
    const float* gin  = (const float*)d_in[0];
    const float* gW   = (const float*)d_in[1];
    const float* gU   = (const float*)d_in[2];
    const float* gb   = (const float*)d_in[3];
    const float* gWd  = (const float*)d_in[4];
    const float* gbd  = (const float*)d_in[5];
    float* gout = (float*)d_out;

    const int B = in_sizes[0] / (TWARM * 2);
    const int blocks = (B + 63) / 64;
    lstm_ar_kernel<<<blocks, 256, 0, stream>>>(gin, gW, gU, gb, gWd, gbd, gout, B);
}

// Round 9
// 738.156 us; speedup vs baseline: 5.0674x; 1.2208x over previous
//
#include <hip/hip_runtime.h>
#include <hip/hip_bf16.h>
#include <hip/hip_fp16.h>

typedef __attribute__((ext_vector_type(8))) short short8;
typedef __attribute__((ext_vector_type(4))) float f32x4;

#define TWARM 96
#define SOUT  24
#define WIN   24   // x staging window (timesteps per per-wave LDS window)
#define NWIN  (TWARM / WIN)
#define K1 1.44269504089f   // log2(e)
#define K2 2.88539008178f   // 2*log2(e)

// Intra-wave LDS write->read ordering fence (rule #18: sched_barrier after waitcnt)
#define LGKM_FENCE() do { \
    asm volatile("s_waitcnt lgkmcnt(0)" ::: "memory"); \
    __builtin_amdgcn_sched_barrier(0); \
} while (0)

static __device__ __forceinline__ short f2bf(float f) {
    __hip_bfloat16 h = __float2bfloat16(f);
    return *reinterpret_cast<short*>(&h);
}
static __device__ __forceinline__ float bf2f(short s) {
    unsigned u = ((unsigned)(unsigned short)s) << 16;
    return __builtin_bit_cast(float, u);
}

// One wave owns 16 batch rows for all 119 steps; after the single init
// barrier, waves are fully independent (per-wave x staging, per-wave pred
// writeout, waitcnt+sched_barrier fencing for the per-wave h LDS round trip).
// Per step: Z' = -K*(x@W + b + H[16][64]@U[64][256]) via 32 MFMAs processed
// in FOUR gate-group quarters (tiles {tt,tt+4,tt+8,tt+12}; acc peak 16 regs)
// to keep the live set under the 128-VGPR spill cliff. U/W/b pre-scaled
// (-log2e, g cols -2*log2e); c kept pre-scaled so gates are exp2() directly.
__global__ void __launch_bounds__(256, 2)
lstm_ar_kernel(const float* __restrict__ gin, const float* __restrict__ gW,
               const float* __restrict__ gU, const float* __restrict__ gb,
               const float* __restrict__ gWd, const float* __restrict__ gbd,
               float* __restrict__ gout, int B)
{
    __shared__ __align__(16) short    U_lds[16384];        // 32 KB, swizzled B-frags
    __shared__ __align__(16) short    h_lds[4][16][72];    // 9 KB, per-wave padded
    __shared__ __align__(16) unsigned x_lds[4][16][WIN];   // 6 KB fp16-pair x; reused for preds
    __shared__ float wdc_lds[4][2][16];                    // 512 B

    const int tid  = threadIdx.x;
    const int wv   = tid >> 6;
    const int lane = tid & 63;
    const int c4   = lane & 15;   // MFMA col / A-row selector
    const int hi   = lane >> 4;   // MFMA k-group / C-row group

    // ---- stage U (coalesced read, swizzled LDS write, gate-scale folded) ----
    for (int idx = tid; idx < 16384; idx += 256) {
        int k = idx >> 8, col = idx & 255;
        float sc = ((col >> 6) == 2) ? -K2 : -K1;   // g columns get -2*log2e
        int dst = (((col >> 4) * 2 + (k >> 5)) * 4 + ((k & 31) >> 3)) * 128
                + (col & 15) * 8 + (k & 7);
        U_lds[dst] = f2bf(sc * gU[idx]);
    }
    // ---- Wd table ----
    if (tid < 128) {
        int tt = tid >> 5, j = (tid >> 4) & 1, cc = tid & 15;
        wdc_lds[tt][j][cc] = gWd[(tt * 16 + cc) * 2 + j];
    }

    // ---- per-lane constants: W and b packed fp16 (scale folded) ----
    unsigned Wp[16], Bp[8];
#pragma unroll
    for (int n = 0; n < 16; ++n) {
        int col = n * 16 + c4;
        float sc = (n >= 8 && n < 12) ? -K2 : -K1;
        __half2 wp = __floats2half2_rn(sc * gW[col], sc * gW[256 + col]);
        Wp[n] = __builtin_bit_cast(unsigned, wp);
    }
#pragma unroll
    for (int m = 0; m < 8; ++m) {
        int n0 = 2 * m, n1 = 2 * m + 1;
        float s0 = (n0 >= 8 && n0 < 12) ? -K2 : -K1;
        float s1 = (n1 >= 8 && n1 < 12) ? -K2 : -K1;
        __half2 bp = __floats2half2_rn(s0 * gb[n0 * 16 + c4], s1 * gb[n1 * 16 + c4]);
        Bp[m] = __builtin_bit_cast(unsigned, bp);
    }
    const float bd0 = gbd[0], bd1 = gbd[1];

    const int row0   = blockIdx.x * 64 + wv * 16;
    const bool active = (row0 + 15) < B;

    // zero this wave's h buffer
    for (int i = lane; i < 16 * 72; i += 64) (&h_lds[wv][0][0])[i] = 0;

    // ---- per-wave x window staging: 16 rows x WIN steps, fp16 pairs ----
    const int xrow = lane >> 2, xq = lane & 3;   // 4 lanes/row, 12 floats each
    auto stage_x = [&](int w) {
        const float* src = gin + (size_t)(row0 + xrow) * (TWARM * 2)
                         + w * (WIN * 2) + xq * 12;
#pragma unroll
        for (int m = 0; m < 3; ++m) {
            float4 v = *reinterpret_cast<const float4*>(src + m * 4);
            uint2 pk;
            pk.x = __builtin_bit_cast(unsigned, __floats2half2_rn(v.x, v.y));
            pk.y = __builtin_bit_cast(unsigned, __floats2half2_rn(v.z, v.w));
            *reinterpret_cast<uint2*>(&x_lds[wv][xrow][xq * 6 + m * 2]) = pk;
        }
        LGKM_FENCE();   // window visible to this wave before first read
    };

    if (active) stage_x(0);
    __syncthreads();    // the ONLY block barrier: U + wdc staged & visible
    if (!active) return;

    float c_[4][4];     // pre-scaled: c' = -K2 * c
#pragma unroll
    for (int tt = 0; tt < 4; ++tt)
#pragma unroll
        for (int r = 0; r < 4; ++r) c_[tt][r] = 0.f;

    const short* hptr  = &h_lds[wv][0][0] + c4 * 72 + hi * 8;     // A-frag read base
    short*       hwptr = &h_lds[wv][0][0] + (hi * 4) * 72 + c4;   // h write base
    const short* uptr  = U_lds + lane * 8;                        // B-frag read base

    float h_[4][4];     // live during decode only

    // ---- one LSTM step; acc is z' = -K*z; four gate-group quarters ----
    auto lstm_step = [&](const float x0[4], const float x1[4], bool save_h) {
        short8 a0v = *reinterpret_cast<const short8*>(hptr);
        short8 a1v = *reinterpret_cast<const short8*>(hptr + 32);
#pragma unroll
        for (int tt = 0; tt < 4; ++tt) {
            f32x4 acc[4];   // tiles n = tt, tt+4, tt+8, tt+12 -> i,f,g,o
#pragma unroll
            for (int j = 0; j < 4; ++j) {
                const int n = tt + 4 * j;
                __half2 wp = __builtin_bit_cast(__half2, Wp[n]);
                float w0 = __low2float(wp), w1 = __high2float(wp);
                __half2 bp = __builtin_bit_cast(__half2, Bp[n >> 1]);
                float bv = (n & 1) ? __high2float(bp) : __low2float(bp);
#pragma unroll
                for (int r = 0; r < 4; ++r)
                    acc[j][r] = fmaf(x1[r], w1, fmaf(x0[r], w0, bv));
            }
#pragma unroll
            for (int j = 0; j < 4; ++j) {
                const int n = tt + 4 * j;
                short8 u0 = *reinterpret_cast<const short8*>(uptr + (n * 2 + 0) * 512);
                short8 u1 = *reinterpret_cast<const short8*>(uptr + (n * 2 + 1) * 512);
                acc[j] = __builtin_amdgcn_mfma_f32_16x16x32_bf16(a0v, u0, acc[j], 0, 0, 0);
                acc[j] = __builtin_amdgcn_mfma_f32_16x16x32_bf16(a1v, u1, acc[j], 0, 0, 0);
            }
            // ea=e^{-zi}, ef=e^{-zf}, eg=e^{-2zg}, eo=e^{-zo}
            // c' update: c'n = sf*c' + (K2*eg - K2)*rcp((1+ea)(1+eg)); ec = exp2(c'n)
#pragma unroll
            for (int r = 0; r < 4; ++r) {
                float ea = __builtin_amdgcn_exp2f(acc[0][r]);
                float ef = __builtin_amdgcn_exp2f(acc[1][r]);
                float eg = __builtin_amdgcn_exp2f(acc[2][r]);
                float eo = __builtin_amdgcn_exp2f(acc[3][r]);
                float sf = __builtin_amdgcn_rcpf(1.0f + ef);
                float sg = fmaf(eg, K2, -K2) *
                    __builtin_amdgcn_rcpf((1.0f + ea) * (1.0f + eg));
                float cn = fmaf(sf, c_[tt][r], sg);
                c_[tt][r] = cn;
                float ec = __builtin_amdgcn_exp2f(cn);
                float hn = (1.0f - ec) *
                    __builtin_amdgcn_rcpf((1.0f + eo) * (1.0f + ec));
                if (save_h) h_[tt][r] = hn;
                hwptr[r * 72 + tt * 16] = f2bf(hn);
            }
        }
        LGKM_FENCE();   // h writes land before next step's A-frag reads
    };

    // ---- warmup: 96 steps, x from this wave's LDS windows ----
#pragma unroll 1
    for (int w = 0; w < NWIN; ++w) {
        if (w != 0) stage_x(w);   // prior step's fence ordered old-window reads
#pragma unroll 1
        for (int tl = 0; tl < WIN; ++tl) {
            float x0[4], x1[4];
#pragma unroll
            for (int r = 0; r < 4; ++r) {
                __half2 hx = __builtin_bit_cast(__half2, x_lds[wv][hi * 4 + r][tl]);
                x0[r] = __low2float(hx);
                x1[r] = __high2float(hx);
            }
            lstm_step(x0, x1, false);
        }
    }

    // rebuild h_ (f32) from the bf16 LDS copy once after warmup
#pragma unroll
    for (int tt = 0; tt < 4; ++tt)
#pragma unroll
        for (int r = 0; r < 4; ++r)
            h_[tt][r] = bf2f((&h_lds[wv][0][0])[(hi * 4 + r) * 72 + tt * 16 + c4]);

    // hoist Wd for this lane's cols (decode-only registers)
    float wdc[4][2];
#pragma unroll
    for (int tt = 0; tt < 4; ++tt) {
        wdc[tt][0] = wdc_lds[tt][0][c4];
        wdc[tt][1] = wdc_lds[tt][1][c4];
    }

    // ---- decode: pred = h@Wd + bd, butterfly over the 16-lane col group ----
    auto make_pred = [&](float* p0, float* p1) {
#pragma unroll
        for (int r = 0; r < 4; ++r) {
            float a0 = 0.f, a1 = 0.f;
#pragma unroll
            for (int tt = 0; tt < 4; ++tt) {
                a0 = fmaf(h_[tt][r], wdc[tt][0], a0);
                a1 = fmaf(h_[tt][r], wdc[tt][1], a1);
            }
            p0[r] = a0; p1[r] = a1;
        }
#pragma unroll
        for (int m = 1; m < 16; m <<= 1)
#pragma unroll
            for (int r = 0; r < 4; ++r) {
                p0[r] += __shfl_xor(p0[r], m, 64);
                p1[r] += __shfl_xor(p1[r], m, 64);
            }
#pragma unroll
        for (int r = 0; r < 4; ++r) { p0[r] += bd0; p1[r] += bd1; }
    };
    // stash pred fp16 in this wave's (dead) x window; feedback stays f32 regs
    auto store_pred = [&](int s, const float* p0, const float* p1) {
        if (c4 == 0) {
#pragma unroll
            for (int r = 0; r < 4; ++r)
                x_lds[wv][hi * 4 + r][s] =
                    __builtin_bit_cast(unsigned, __floats2half2_rn(p0[r], p1[r]));
        }
    };

    float p0[4], p1[4];
    make_pred(p0, p1);
    store_pred(0, p0, p1);
#pragma unroll 1
    for (int s = 1; s < SOUT; ++s) {
        lstm_step(p0, p1, true);
        make_pred(p0, p1);
        store_pred(s, p0, p1);
    }
    LGKM_FENCE();   // all pred stashes of this wave visible to this wave

    // ---- per-wave coalesced writeout: 16 rows x 48 floats ----
#pragma unroll
    for (int m = 0; m < 6; ++m) {
        unsigned u = x_lds[wv][xrow][xq * 6 + m];
        __half2 hv = __builtin_bit_cast(__half2, u);
        *reinterpret_cast<float2*>(
            gout + (size_t)(row0 + xrow) * (SOUT * 2) + xq * 12 + m * 2) =
            make_float2(__low2float(hv), __high2float(hv));
    }
}

extern "C" void kernel_launch(void* const* d_in, const int* in_sizes, int n_in,
                              void* d_out, int out_size, void* d_ws, size_t ws_size,
                              hipStream_t stream) {
    const float* gin  = (const float*)d_in[0];
    const float* gW   = (const float*)d_in[1];
    const float* gU   = (const float*)d_in[2];
    const float* gb   = (const float*)d_in[3];
    const float* gWd  = (const float*)d_in[4];
    const float* gbd  = (const float*)d_in[5];
    float* gout = (float*)d_out;

    const int B = in_sizes[0] / (TWARM * 2);
    const int blocks = (B + 63) / 64;
    lstm_ar_kernel<<<blocks, 256, 0, stream>>>(gin, gW, gU, gb, gWd, gbd, gout, B);
}

// Round 10
// 719.915 us; speedup vs baseline: 5.1958x; 1.0253x over previous
//
#include <hip/hip_runtime.h>
#include <hip/hip_bf16.h>
#include <hip/hip_fp16.h>

typedef __attribute__((ext_vector_type(8))) short short8;
typedef __attribute__((ext_vector_type(4))) float f32x4;

#define TWARM 96
#define SOUT  24
#define WIN   24   // x staging window (timesteps per per-wave LDS window)
#define NWIN  (TWARM / WIN)
#define K1 1.44269504089f   // log2(e)
#define K2 2.88539008178f   // 2*log2(e)

// Intra-wave LDS write->read ordering fence (rule #18: sched_barrier after waitcnt)
#define LGKM_FENCE() do { \
    asm volatile("s_waitcnt lgkmcnt(0)" ::: "memory"); \
    __builtin_amdgcn_sched_barrier(0); \
} while (0)

static __device__ __forceinline__ short f2bf(float f) {
    __hip_bfloat16 h = __float2bfloat16(f);
    return *reinterpret_cast<short*>(&h);
}
static __device__ __forceinline__ float bf2f(short s) {
    unsigned u = ((unsigned)(unsigned short)s) << 16;
    return __builtin_bit_cast(float, u);
}

// One wave owns 16 batch rows for all 119 steps; after the single init
// barrier, waves are fully independent (per-wave x staging, per-wave pred
// writeout, waitcnt+sched_barrier fencing for the per-wave h LDS round trip).
// Per step: Z' = -K*(x@W + b + H[16][64]@U[64][256]) via 32 MFMAs processed
// in FOUR gate-group quarters (tiles {tt,tt+4,tt+8,tt+12}; acc peak 16 regs).
// waves_per_eu(2,2): pin the allocator's occupancy target so it uses the full
// 256-VGPR budget instead of squeezing to 128 and spilling (r7/r9 FETCH bloat).
__global__ void __attribute__((amdgpu_flat_work_group_size(256, 256),
                               amdgpu_waves_per_eu(2, 2)))
lstm_ar_kernel(const float* __restrict__ gin, const float* __restrict__ gW,
               const float* __restrict__ gU, const float* __restrict__ gb,
               const float* __restrict__ gWd, const float* __restrict__ gbd,
               float* __restrict__ gout, int B)
{
    __shared__ __align__(16) short    U_lds[16384];        // 32 KB, swizzled B-frags
    __shared__ __align__(16) short    h_lds[4][16][72];    // 9 KB, per-wave padded
    __shared__ __align__(16) unsigned x_lds[4][16][WIN];   // 6 KB fp16-pair x; reused for preds
    __shared__ float wdc_lds[4][2][16];                    // 512 B

    const int tid  = threadIdx.x;
    const int wv   = tid >> 6;
    const int lane = tid & 63;
    const int c4   = lane & 15;   // MFMA col / A-row selector
    const int hi   = lane >> 4;   // MFMA k-group / C-row group

    // ---- stage U (coalesced read, swizzled LDS write, gate-scale folded) ----
    for (int idx = tid; idx < 16384; idx += 256) {
        int k = idx >> 8, col = idx & 255;
        float sc = ((col >> 6) == 2) ? -K2 : -K1;   // g columns get -2*log2e
        int dst = (((col >> 4) * 2 + (k >> 5)) * 4 + ((k & 31) >> 3)) * 128
                + (col & 15) * 8 + (k & 7);
        U_lds[dst] = f2bf(sc * gU[idx]);
    }
    // ---- Wd table ----
    if (tid < 128) {
        int tt = tid >> 5, j = (tid >> 4) & 1, cc = tid & 15;
        wdc_lds[tt][j][cc] = gWd[(tt * 16 + cc) * 2 + j];
    }

    // ---- per-lane constants: W and b packed fp16 (scale folded) ----
    unsigned Wp[16], Bp[8];
#pragma unroll
    for (int n = 0; n < 16; ++n) {
        int col = n * 16 + c4;
        float sc = (n >= 8 && n < 12) ? -K2 : -K1;
        __half2 wp = __floats2half2_rn(sc * gW[col], sc * gW[256 + col]);
        Wp[n] = __builtin_bit_cast(unsigned, wp);
    }
#pragma unroll
    for (int m = 0; m < 8; ++m) {
        int n0 = 2 * m, n1 = 2 * m + 1;
        float s0 = (n0 >= 8 && n0 < 12) ? -K2 : -K1;
        float s1 = (n1 >= 8 && n1 < 12) ? -K2 : -K1;
        __half2 bp = __floats2half2_rn(s0 * gb[n0 * 16 + c4], s1 * gb[n1 * 16 + c4]);
        Bp[m] = __builtin_bit_cast(unsigned, bp);
    }
    const float bd0 = gbd[0], bd1 = gbd[1];

    const int row0   = blockIdx.x * 64 + wv * 16;
    const bool active = (row0 + 15) < B;

    // zero this wave's h buffer
    for (int i = lane; i < 16 * 72; i += 64) (&h_lds[wv][0][0])[i] = 0;

    // ---- per-wave x window staging: 16 rows x WIN steps, fp16 pairs ----
    const int xrow = lane >> 2, xq = lane & 3;   // 4 lanes/row, 12 floats each
    auto stage_x = [&](int w) {
        const float* src = gin + (size_t)(row0 + xrow) * (TWARM * 2)
                         + w * (WIN * 2) + xq * 12;
#pragma unroll
        for (int m = 0; m < 3; ++m) {
            float4 v = *reinterpret_cast<const float4*>(src + m * 4);
            uint2 pk;
            pk.x = __builtin_bit_cast(unsigned, __floats2half2_rn(v.x, v.y));
            pk.y = __builtin_bit_cast(unsigned, __floats2half2_rn(v.z, v.w));
            *reinterpret_cast<uint2*>(&x_lds[wv][xrow][xq * 6 + m * 2]) = pk;
        }
        LGKM_FENCE();   // window visible to this wave before first read
    };

    if (active) stage_x(0);
    __syncthreads();    // the ONLY block barrier: U + wdc staged & visible
    if (!active) return;

    float c_[4][4];     // pre-scaled: c' = -K2 * c
#pragma unroll
    for (int tt = 0; tt < 4; ++tt)
#pragma unroll
        for (int r = 0; r < 4; ++r) c_[tt][r] = 0.f;

    const short* hptr  = &h_lds[wv][0][0] + c4 * 72 + hi * 8;     // A-frag read base
    short*       hwptr = &h_lds[wv][0][0] + (hi * 4) * 72 + c4;   // h write base
    const short* uptr  = U_lds + lane * 8;                        // B-frag read base

    float h_[4][4];     // live during decode only

    // ---- one LSTM step; acc is z' = -K*z; four gate-group quarters ----
    auto lstm_step = [&](const float x0[4], const float x1[4], bool save_h) {
        short8 a0v = *reinterpret_cast<const short8*>(hptr);
        short8 a1v = *reinterpret_cast<const short8*>(hptr + 32);
#pragma unroll
        for (int tt = 0; tt < 4; ++tt) {
            f32x4 acc[4];   // tiles n = tt, tt+4, tt+8, tt+12 -> i,f,g,o
#pragma unroll
            for (int j = 0; j < 4; ++j) {
                const int n = tt + 4 * j;
                __half2 wp = __builtin_bit_cast(__half2, Wp[n]);
                float w0 = __low2float(wp), w1 = __high2float(wp);
                __half2 bp = __builtin_bit_cast(__half2, Bp[n >> 1]);
                float bv = (n & 1) ? __high2float(bp) : __low2float(bp);
#pragma unroll
                for (int r = 0; r < 4; ++r)
                    acc[j][r] = fmaf(x1[r], w1, fmaf(x0[r], w0, bv));
            }
#pragma unroll
            for (int j = 0; j < 4; ++j) {
                const int n = tt + 4 * j;
                short8 u0 = *reinterpret_cast<const short8*>(uptr + (n * 2 + 0) * 512);
                short8 u1 = *reinterpret_cast<const short8*>(uptr + (n * 2 + 1) * 512);
                acc[j] = __builtin_amdgcn_mfma_f32_16x16x32_bf16(a0v, u0, acc[j], 0, 0, 0);
                acc[j] = __builtin_amdgcn_mfma_f32_16x16x32_bf16(a1v, u1, acc[j], 0, 0, 0);
            }
            // ea=e^{-zi}, ef=e^{-zf}, eg=e^{-2zg}, eo=e^{-zo}
            // c' update: c'n = sf*c' + (K2*eg - K2)*rcp((1+ea)(1+eg)); ec = exp2(c'n)
#pragma unroll
            for (int r = 0; r < 4; ++r) {
                float ea = __builtin_amdgcn_exp2f(acc[0][r]);
                float ef = __builtin_amdgcn_exp2f(acc[1][r]);
                float eg = __builtin_amdgcn_exp2f(acc[2][r]);
                float eo = __builtin_amdgcn_exp2f(acc[3][r]);
                float sf = __builtin_amdgcn_rcpf(1.0f + ef);
                float sg = fmaf(eg, K2, -K2) *
                    __builtin_amdgcn_rcpf((1.0f + ea) * (1.0f + eg));
                float cn = fmaf(sf, c_[tt][r], sg);
                c_[tt][r] = cn;
                float ec = __builtin_amdgcn_exp2f(cn);
                float hn = (1.0f - ec) *
                    __builtin_amdgcn_rcpf((1.0f + eo) * (1.0f + ec));
                if (save_h) h_[tt][r] = hn;
                hwptr[r * 72 + tt * 16] = f2bf(hn);
            }
        }
        LGKM_FENCE();   // h writes land before next step's A-frag reads
    };

    // ---- warmup: 96 steps, x from this wave's LDS windows ----
#pragma unroll 1
    for (int w = 0; w < NWIN; ++w) {
        if (w != 0) stage_x(w);   // prior step's fence ordered old-window reads
#pragma unroll 1
        for (int tl = 0; tl < WIN; ++tl) {
            float x0[4], x1[4];
#pragma unroll
            for (int r = 0; r < 4; ++r) {
                __half2 hx = __builtin_bit_cast(__half2, x_lds[wv][hi * 4 + r][tl]);
                x0[r] = __low2float(hx);
                x1[r] = __high2float(hx);
            }
            lstm_step(x0, x1, false);
        }
    }

    // rebuild h_ (f32) from the bf16 LDS copy once after warmup
#pragma unroll
    for (int tt = 0; tt < 4; ++tt)
#pragma unroll
        for (int r = 0; r < 4; ++r)
            h_[tt][r] = bf2f((&h_lds[wv][0][0])[(hi * 4 + r) * 72 + tt * 16 + c4]);

    // hoist Wd for this lane's cols (decode-only registers)
    float wdc[4][2];
#pragma unroll
    for (int tt = 0; tt < 4; ++tt) {
        wdc[tt][0] = wdc_lds[tt][0][c4];
        wdc[tt][1] = wdc_lds[tt][1][c4];
    }

    // ---- decode: pred = h@Wd + bd, butterfly over the 16-lane col group ----
    auto make_pred = [&](float* p0, float* p1) {
#pragma unroll
        for (int r = 0; r < 4; ++r) {
            float a0 = 0.f, a1 = 0.f;
#pragma unroll
            for (int tt = 0; tt < 4; ++tt) {
                a0 = fmaf(h_[tt][r], wdc[tt][0], a0);
                a1 = fmaf(h_[tt][r], wdc[tt][1], a1);
            }
            p0[r] = a0; p1[r] = a1;
        }
#pragma unroll
        for (int m = 1; m < 16; m <<= 1)
#pragma unroll
            for (int r = 0; r < 4; ++r) {
                p0[r] += __shfl_xor(p0[r], m, 64);
                p1[r] += __shfl_xor(p1[r], m, 64);
            }
#pragma unroll
        for (int r = 0; r < 4; ++r) { p0[r] += bd0; p1[r] += bd1; }
    };
    // stash pred fp16 in this wave's (dead) x window; feedback stays f32 regs
    auto store_pred = [&](int s, const float* p0, const float* p1) {
        if (c4 == 0) {
#pragma unroll
            for (int r = 0; r < 4; ++r)
                x_lds[wv][hi * 4 + r][s] =
                    __builtin_bit_cast(unsigned, __floats2half2_rn(p0[r], p1[r]));
        }
    };

    float p0[4], p1[4];
    make_pred(p0, p1);
    store_pred(0, p0, p1);
#pragma unroll 1
    for (int s = 1; s < SOUT; ++s) {
        lstm_step(p0, p1, true);
        make_pred(p0, p1);
        store_pred(s, p0, p1);
    }
    LGKM_FENCE();   // all pred stashes of this wave visible to this wave

    // ---- per-wave coalesced writeout: 16 rows x 48 floats ----
#pragma unroll
    for (int m = 0; m < 6; ++m) {
        unsigned u = x_lds[wv][xrow][xq * 6 + m];
        __half2 hv = __builtin_bit_cast(__half2, u);
        *reinterpret_cast<float2*>(
            gout + (size_t)(row0 + xrow) * (SOUT * 2) + xq * 12 + m * 2) =
            make_float2(__low2float(hv), __high2float(hv));
    }
}

extern "C" void kernel_launch(void* const* d_in, const int* in_sizes, int n_in,
                              void* d_out, int out_size, void* d_ws, size_t ws_size,
                              hipStream_t stream) {
    const float* gin  = (const float*)d_in[0];
    const float* gW   = (const float*)d_in[1];
    const float* gU   = (const float*)d_in[2];
    const float* gb   = (const float*)d_in[3];
    const float* gWd  = (const float*)d_in[4];
    const float* gbd  = (const float*)d_in[5];
    float* gout = (float*)d_out;

    const int B = in_sizes[0] / (TWARM * 2);
    const int blocks = (B + 63) / 64;
    lstm_ar_kernel<<<blocks, 256, 0, stream>>>(gin, gW, gU, gb, gWd, gbd, gout, B);
}